// Round 5
// baseline (1291.506 us; speedup 1.0000x reference)
//
#include <hip/hip_runtime.h>

#define NEG_SLOPE 0.2f
#define NRANGE 8          // dst-range partitions == XCD count (b%8 heuristic)
#define BSH 6             // bucket shift: 64 nodes per bucket
#define BRS 64            // bucket node-range size

__device__ __forceinline__ float elu_f(float x) {
    return x > 0.f ? x : __expf(x) - 1.f;
}
__device__ __forceinline__ float lrelu_f(float x) {
    return x > 0.f ? x : NEG_SLOPE * x;
}

// ---------------------------------------------------------------------------
// Radix step 1: histogram of coarse dst-buckets (782 counters, low contention).
// ---------------------------------------------------------------------------
__global__ __launch_bounds__(256) void bucket_count_kernel(
    const int* __restrict__ ei, int* __restrict__ bcnt, int E)
{
    int t = blockIdx.x * 256 + threadIdx.x;
    if (t < E) atomicAdd(&bcnt[__builtin_nontemporal_load(&ei[E + t]) >> BSH], 1);
}

// ---------------------------------------------------------------------------
// Radix step 2: exclusive scan of NB (<1024) bucket counts, one block.
// Writes bbase[0..NB], pair-cursor init, rowptr[N]=E.
// ---------------------------------------------------------------------------
__global__ __launch_bounds__(1024) void bucket_scan_kernel(
    const int* __restrict__ bcnt, int* __restrict__ bbase,
    int* __restrict__ gcur, int* __restrict__ rowptr, int NB, int N, int E)
{
    __shared__ int part[1024];
    int t = threadIdx.x;
    part[t] = (t < NB) ? bcnt[t] : 0;
    __syncthreads();
    for (int off = 1; off < 1024; off <<= 1) {
        int v = (t >= off) ? part[t - off] : 0;
        __syncthreads();
        part[t] += v;
        __syncthreads();
    }
    int excl = (t == 0) ? 0 : part[t - 1];
    if (t < NB) { bbase[t] = excl; gcur[t] = excl; }
    if (t == NB) bbase[NB] = part[NB - 1];
    if (t == 0) rowptr[N] = E;
}

// ---------------------------------------------------------------------------
// Radix step 3: partition edges into bucket-grouped (src,dst) pairs.
// XCD-range-affine; bucket-level cursors mean consecutive slots of a region
// are claimed+written back-to-back -> 64B lines fill fully in one XCD's L2.
// ---------------------------------------------------------------------------
__global__ __launch_bounds__(256) void partition_kernel(
    const int* __restrict__ ei, int* __restrict__ gcur,
    int2* __restrict__ pairs, int E, int N, int nChunks)
{
    int b = blockIdx.x;
    int range = b & (NRANGE - 1);
    int chunk = b >> 3;
    int RS = (N + NRANGE - 1) / NRANGE;
    int lo = range * RS;
    int hi = lo + RS; if (hi > N) hi = N;
    int per = (E + nChunks - 1) / nChunks;
    int beg = chunk * per;
    int end = beg + per; if (end > E) end = E;
    for (int i = beg + (int)threadIdx.x; i < end; i += 256) {
        int dst = __builtin_nontemporal_load(&ei[E + i]);
        if (dst >= lo && dst < hi) {
            int src = __builtin_nontemporal_load(&ei[i]);
            int pos = atomicAdd(&gcur[dst >> BSH], 1);
            pairs[pos] = make_int2(src, dst);
        }
    }
}

// ---------------------------------------------------------------------------
// Radix step 4: per-bucket CSR build. One block per bucket: LDS hist over the
// bucket's 64 nodes, serial scan, write rowptr slice, scatter src into the
// bucket's private srclist region (single writer, short window -> full lines).
// ---------------------------------------------------------------------------
__global__ __launch_bounds__(256) void build_kernel(
    const int2* __restrict__ pairs, const int* __restrict__ bbase,
    int* __restrict__ rowptr, int* __restrict__ srclist, int N)
{
    __shared__ int hist[BRS];
    __shared__ int cur[BRS];
    int b = blockIdx.x;
    int lo = b << BSH;
    int nn = N - lo; if (nn > BRS) nn = BRS;
    int tid = threadIdx.x;
    if (tid < BRS) hist[tid] = 0;
    __syncthreads();
    int pbeg = bbase[b], pend = bbase[b + 1];
    for (int i = pbeg + tid; i < pend; i += 256)
        atomicAdd(&hist[pairs[i].y - lo], 1);
    __syncthreads();
    if (tid == 0) {
        int run = pbeg;
        for (int j = 0; j < nn; ++j) {
            cur[j] = run;
            rowptr[lo + j] = run;
            run += hist[j];
        }
    }
    __syncthreads();
    for (int i = pbeg + tid; i < pend; i += 256) {
        int2 p = pairs[i];
        int pos = atomicAdd(&cur[p.y - lo], 1);
        srclist[pos] = p.x;
    }
}

// ---------------------------------------------------------------------------
// GEMM1: h1 = x @ W1  ([N,64] x [64,64]) with fused alpha_src1/alpha_dst1
// ---------------------------------------------------------------------------
__global__ __launch_bounds__(256) void gemm1_kernel(
    const float* __restrict__ x, const float* __restrict__ W,
    const float* __restrict__ a_src, const float* __restrict__ a_dst,
    float* __restrict__ h1, float* __restrict__ as1, float* __restrict__ ad1,
    int N)
{
    __shared__ float Wl[64 * 64];
    __shared__ float Xl[4][64];
    int tid = threadIdx.x;
    for (int i = tid; i < 64 * 64; i += 256) Wl[i] = W[i];
    int r   = tid >> 6;
    int col = tid & 63;
    int row = blockIdx.x * 4 + r;
    if (row < N) Xl[r][col] = x[(size_t)row * 64 + col];
    __syncthreads();
    if (row >= N) return;

    float acc = 0.f;
#pragma unroll
    for (int k = 0; k < 64; ++k) acc += Xl[r][k] * Wl[k * 64 + col];
    h1[(size_t)row * 64 + col] = acc;

    int head = col >> 5;
    float ps = acc * a_src[col];
    float pd = acc * a_dst[col];
#pragma unroll
    for (int off = 16; off; off >>= 1) {
        ps += __shfl_xor(ps, off, 32);
        pd += __shfl_xor(pd, off, 32);
    }
    if ((col & 31) == 0) {
        as1[row * 2 + head] = ps;
        ad1[row * 2 + head] = pd;
    }
}

// ---------------------------------------------------------------------------
// Layer-1 aggregation, gather-side: one 64-lane wave per dst node.
// ---------------------------------------------------------------------------
__global__ __launch_bounds__(256) void agg1_kernel(
    const int* __restrict__ rowptr, const int* __restrict__ srclist,
    const float* __restrict__ h1, const float* __restrict__ as1,
    const float* __restrict__ ad1, const float* __restrict__ b1,
    float* __restrict__ h1e, int N)
{
    int n = (blockIdx.x * 256 + threadIdx.x) >> 6;
    int lane = threadIdx.x & 63;
    if (n >= N) return;
    int head = lane >> 5;
    float adn = ad1[n * 2 + head];

    float w = __expf(lrelu_f(as1[n * 2 + head] + adn));
    float den = w;
    float acc = w * h1[(size_t)n * 64 + lane];

    int i = rowptr[n], endp = rowptr[n + 1];
    for (; i + 3 < endp; i += 4) {
        int s0 = srclist[i], s1 = srclist[i + 1];
        int s2 = srclist[i + 2], s3 = srclist[i + 3];
        float a0 = as1[s0 * 2 + head], a1 = as1[s1 * 2 + head];
        float a2 = as1[s2 * 2 + head], a3 = as1[s3 * 2 + head];
        float g0 = h1[(size_t)s0 * 64 + lane];
        float g1 = h1[(size_t)s1 * 64 + lane];
        float g2 = h1[(size_t)s2 * 64 + lane];
        float g3 = h1[(size_t)s3 * 64 + lane];
        float w0 = __expf(lrelu_f(a0 + adn));
        float w1 = __expf(lrelu_f(a1 + adn));
        float w2 = __expf(lrelu_f(a2 + adn));
        float w3 = __expf(lrelu_f(a3 + adn));
        den += (w0 + w1) + (w2 + w3);
        acc += w0 * g0 + w1 * g1 + w2 * g2 + w3 * g3;
    }
    for (; i < endp; ++i) {
        int s0 = srclist[i];
        float w0 = __expf(lrelu_f(as1[s0 * 2 + head] + adn));
        den += w0;
        acc += w0 * h1[(size_t)s0 * 64 + lane];
    }

    float v = acc / den + b1[lane];
    h1e[(size_t)n * 64 + lane] = elu_f(v);
}

// ---------------------------------------------------------------------------
// GEMM2: h2 = h1e @ W2 ([N,64] x [64,32]) with fused alpha2 reductions
// ---------------------------------------------------------------------------
__global__ __launch_bounds__(256) void gemm2_kernel(
    const float* __restrict__ xin, const float* __restrict__ W,
    const float* __restrict__ a_src, const float* __restrict__ a_dst,
    float* __restrict__ h2, float* __restrict__ as2, float* __restrict__ ad2,
    int N)
{
    __shared__ float Wl[64 * 32];
    __shared__ float Xl[8][64];
    int tid = threadIdx.x;
    for (int i = tid; i < 64 * 32; i += 256) Wl[i] = W[i];
    int base = blockIdx.x * 8;
    for (int i = tid; i < 8 * 64; i += 256) {
        int rr = i >> 6, cc = i & 63;
        if (base + rr < N) Xl[rr][cc] = xin[(size_t)(base + rr) * 64 + cc];
    }
    __syncthreads();
    int r   = tid >> 5;
    int col = tid & 31;
    int row = base + r;
    if (row >= N) return;

    float acc = 0.f;
#pragma unroll
    for (int k = 0; k < 64; ++k) acc += Xl[r][k] * Wl[k * 32 + col];
    h2[(size_t)row * 32 + col] = acc;

    float ps = acc * a_src[col];
    float pd = acc * a_dst[col];
#pragma unroll
    for (int off = 16; off; off >>= 1) {
        ps += __shfl_xor(ps, off, 32);
        pd += __shfl_xor(pd, off, 32);
    }
    if (col == 0) { as2[row] = ps; ad2[row] = pd; }
}

// ---------------------------------------------------------------------------
// Layer-2 aggregation, gather-side: 32 lanes per dst node, 4x unrolled.
// out layout: [0,N) scores, [N, N+N*32) h
// ---------------------------------------------------------------------------
__global__ __launch_bounds__(256) void agg2_kernel(
    const int* __restrict__ rowptr, const int* __restrict__ srclist,
    const float* __restrict__ h2, const float* __restrict__ as2,
    const float* __restrict__ ad2, const float* __restrict__ b2,
    const float* __restrict__ fcW, const float* __restrict__ fcb,
    float* __restrict__ out, int N)
{
    int g = blockIdx.x * 256 + threadIdx.x;
    int n = g >> 5;
    int lane = g & 31;
    if (n >= N) return;
    float adn = ad2[n];

    float w = __expf(lrelu_f(as2[n] + adn));
    float den = w;
    float acc = w * h2[(size_t)n * 32 + lane];

    int i = rowptr[n], endp = rowptr[n + 1];
    for (; i + 3 < endp; i += 4) {
        int s0 = srclist[i], s1 = srclist[i + 1];
        int s2 = srclist[i + 2], s3 = srclist[i + 3];
        float a0 = as2[s0], a1 = as2[s1], a2 = as2[s2], a3 = as2[s3];
        float g0 = h2[(size_t)s0 * 32 + lane];
        float g1 = h2[(size_t)s1 * 32 + lane];
        float g2 = h2[(size_t)s2 * 32 + lane];
        float g3 = h2[(size_t)s3 * 32 + lane];
        float w0 = __expf(lrelu_f(a0 + adn));
        float w1 = __expf(lrelu_f(a1 + adn));
        float w2 = __expf(lrelu_f(a2 + adn));
        float w3 = __expf(lrelu_f(a3 + adn));
        den += (w0 + w1) + (w2 + w3);
        acc += w0 * g0 + w1 * g1 + w2 * g2 + w3 * g3;
    }
    for (; i < endp; ++i) {
        int s0 = srclist[i];
        float w0 = __expf(lrelu_f(as2[s0] + adn));
        den += w0;
        acc += w0 * h2[(size_t)s0 * 32 + lane];
    }

    float v = elu_f(acc / den + b2[lane]);
    out[(size_t)N + (size_t)n * 32 + lane] = v;
    float p = v * fcW[lane];
#pragma unroll
    for (int off = 16; off; off >>= 1) p += __shfl_xor(p, off, 32);
    if (lane == 0) out[n] = p + fcb[0];
}

extern "C" void kernel_launch(void* const* d_in, const int* in_sizes, int n_in,
                              void* d_out, int out_size, void* d_ws, size_t ws_size,
                              hipStream_t stream) {
    const float* x    = (const float*)d_in[0];
    const int*   ei   = (const int*)d_in[1];
    const float* W1   = (const float*)d_in[2];
    const float* a_s1 = (const float*)d_in[3];
    const float* a_d1 = (const float*)d_in[4];
    const float* b1   = (const float*)d_in[5];
    const float* W2   = (const float*)d_in[6];
    const float* a_s2 = (const float*)d_in[7];
    const float* a_d2 = (const float*)d_in[8];
    const float* b2   = (const float*)d_in[9];
    const float* fcW  = (const float*)d_in[10];
    const float* fcb  = (const float*)d_in[11];

    const int N = in_sizes[0] / 64;
    const int E = in_sizes[1] / 2;
    const int NB = (N + BRS - 1) >> BSH;   // 782 for N=50000 (must be < 1024)

    float* fws  = (float*)d_ws;
    float* h1   = fws;                      // N*64  (reused as h2 after agg1)
    float* h1e  = h1   + (size_t)N * 64;    // N*64
    float* as1  = h1e  + (size_t)N * 64;    // N*2
    float* ad1  = as1  + (size_t)N * 2;     // N*2
    float* as2  = ad1  + (size_t)N * 2;     // N
    float* ad2  = as2  + (size_t)N;         // N
    int*   bcnt    = (int*)(ad2 + (size_t)N);  // NB (histogram)
    int*   bbase   = bcnt + NB;                // NB+1
    int*   gcur    = bbase + NB + 1;           // NB (pair cursors)
    int*   rowptr  = gcur + NB;                // N+1
    int*   srclist = rowptr + N + 1;           // E
    // 8B-aligned pairs region
    uintptr_t pa = (uintptr_t)(srclist + E);
    pa = (pa + 7) & ~(uintptr_t)7;
    int2*  pairs   = (int2*)pa;                // E pairs
    float* h2   = h1;                      // alias: h1 dead after agg1

    hipMemsetAsync(bcnt, 0, sizeof(int) * (size_t)NB, stream);

    bucket_count_kernel<<<(E + 255) / 256, 256, 0, stream>>>(ei, bcnt, E);
    bucket_scan_kernel<<<1, 1024, 0, stream>>>(bcnt, bbase, gcur, rowptr, NB, N, E);

    const int nChunks = 256;  // 256 chunks x 8 ranges = 2048 blocks
    partition_kernel<<<nChunks * NRANGE, 256, 0, stream>>>(ei, gcur, pairs, E, N, nChunks);

    build_kernel<<<NB, 256, 0, stream>>>(pairs, bbase, rowptr, srclist, N);

    gemm1_kernel<<<(N + 3) / 4, 256, 0, stream>>>(x, W1, a_s1, a_d1, h1, as1, ad1, N);

    agg1_kernel<<<((size_t)N * 64 + 255) / 256, 256, 0, stream>>>(
        rowptr, srclist, h1, as1, ad1, b1, h1e, N);

    gemm2_kernel<<<(N + 7) / 8, 256, 0, stream>>>(h1e, W2, a_s2, a_d2, h2, as2, ad2, N);

    agg2_kernel<<<((size_t)N * 32 + 255) / 256, 256, 0, stream>>>(
        rowptr, srclist, h2, as2, ad2, b2, fcW, fcb, (float*)d_out, N);
}

// Round 6
// 389.639 us; speedup vs baseline: 3.3146x; 3.3146x over previous
//
#include <hip/hip_runtime.h>

#define NEG_SLOPE 0.2f
#define NRANGE 8          // dst-range partitions == XCD count (b%8 heuristic)
#define SCAN_TILE 2048    // elements per scan block

__device__ __forceinline__ float elu_f(float x) {
    return x > 0.f ? x : __expf(x) - 1.f;
}
__device__ __forceinline__ float lrelu_f(float x) {
    return x > 0.f ? x : NEG_SLOPE * x;
}

// ---------------------------------------------------------------------------
// CSR build step 1: histogram of destination nodes (real edges only).
// Per-NODE counters: 50K counters, ~32 atomics each — low contention.
// (Round-4 lesson: 782 bucket counters => ~2100 serialized atomic-returns
//  each => 8x regression. Keep cursors fine-grained.)
// ---------------------------------------------------------------------------
__global__ __launch_bounds__(256) void hist_kernel(
    const int* __restrict__ ei, int* __restrict__ cnt, int E)
{
    int t = blockIdx.x * 256 + threadIdx.x;
    if (t < E) atomicAdd(&cnt[__builtin_nontemporal_load(&ei[E + t])], 1);
}

// ---------------------------------------------------------------------------
// Hierarchical scan phase A: per-tile sums (coalesced reads + block reduce).
// ---------------------------------------------------------------------------
__global__ __launch_bounds__(256) void scan_partial_kernel(
    const int* __restrict__ cnt, int* __restrict__ blocksum, int N)
{
    __shared__ int red[256];
    int base = blockIdx.x * SCAN_TILE;
    int s = 0;
#pragma unroll
    for (int k = 0; k < 8; ++k) {
        int i = base + k * 256 + threadIdx.x;
        if (i < N) s += cnt[i];
    }
    red[threadIdx.x] = s;
    __syncthreads();
    for (int off = 128; off; off >>= 1) {
        if (threadIdx.x < off) red[threadIdx.x] += red[threadIdx.x + off];
        __syncthreads();
    }
    if (threadIdx.x == 0) blocksum[blockIdx.x] = red[0];
}

// ---------------------------------------------------------------------------
// Hierarchical scan phase B: exclusive scan of tile sums (nb <= 1024),
// one tiny block; also writes rowptr[N] = E.
// ---------------------------------------------------------------------------
__global__ __launch_bounds__(1024) void scan_blocksum_kernel(
    int* __restrict__ blocksum, int nb, int* __restrict__ rowptr, int N, int E)
{
    __shared__ int part[1024];
    int t = threadIdx.x;
    part[t] = (t < nb) ? blocksum[t] : 0;
    __syncthreads();
    for (int off = 1; off < 1024; off <<= 1) {
        int v = (t >= off) ? part[t - off] : 0;
        __syncthreads();
        part[t] += v;
        __syncthreads();
    }
    if (t < nb) blocksum[t] = (t == 0) ? 0 : part[t - 1];  // exclusive
    if (t == 0) rowptr[N] = E;
}

// ---------------------------------------------------------------------------
// Hierarchical scan phase C: block-local exclusive scan of each tile + tile
// offset; writes rowptr and scatter cursor (cursor aliases cnt).
// ---------------------------------------------------------------------------
__global__ __launch_bounds__(256) void scan_final_kernel(
    int* __restrict__ cnt, const int* __restrict__ blocksum,
    int* __restrict__ rowptr, int N)
{
    __shared__ int lds[SCAN_TILE];
    __shared__ int tsum[256];
    int base = blockIdx.x * SCAN_TILE;
    int tid = threadIdx.x;
#pragma unroll
    for (int k = 0; k < 8; ++k) {
        int i = base + k * 256 + tid;
        lds[k * 256 + tid] = (i < N) ? cnt[i] : 0;
    }
    __syncthreads();
    int my[8];
    int s = 0;
#pragma unroll
    for (int j = 0; j < 8; ++j) { my[j] = s; s += lds[tid * 8 + j]; }
    tsum[tid] = s;
    __syncthreads();
    for (int off = 1; off < 256; off <<= 1) {
        int v = (tid >= off) ? tsum[tid - off] : 0;
        __syncthreads();
        tsum[tid] += v;
        __syncthreads();
    }
    int texcl = (tid == 0) ? 0 : tsum[tid - 1];
    int boff = blocksum[blockIdx.x];
    __syncthreads();
#pragma unroll
    for (int j = 0; j < 8; ++j) lds[tid * 8 + j] = boff + texcl + my[j];
    __syncthreads();
#pragma unroll
    for (int k = 0; k < 8; ++k) {
        int i = base + k * 256 + tid;
        if (i < N) {
            int v = lds[k * 256 + tid];
            rowptr[i] = v;
            cnt[i] = v;      // scatter cursor
        }
    }
}

// ---------------------------------------------------------------------------
// Fused: CSR scatter (blocks [0, nChunks*NRANGE)) + GEMM1 (remaining blocks).
// Independent work; scatter is atomic-latency bound (VALUBusy ~4%), gemm1 is
// VALU/LDS bound — co-residency hides gemm1 entirely under scatter.
// GEMM1: h1 = x @ W1 ([N,64]x[64,64]) + fused alpha_src1/alpha_dst1.
// ---------------------------------------------------------------------------
__global__ __launch_bounds__(256) void scatter_gemm1_kernel(
    const int* __restrict__ ei, int* __restrict__ cursor,
    int* __restrict__ srclist, int E, int N, int nChunks,
    const float* __restrict__ x, const float* __restrict__ W,
    const float* __restrict__ a_src, const float* __restrict__ a_dst,
    float* __restrict__ h1, float* __restrict__ as1, float* __restrict__ ad1)
{
    __shared__ float Wl[64 * 64];
    __shared__ float Xl[4][64];
    int b = blockIdx.x;
    int nScatter = nChunks * NRANGE;
    if (b < nScatter) {
        // ---- scatter path (XCD-range-affine via b%8, per-node cursors) ----
        int range = b & (NRANGE - 1);
        int chunk = b >> 3;
        int RS = (N + NRANGE - 1) / NRANGE;
        int lo = range * RS;
        int hi = lo + RS; if (hi > N) hi = N;
        int per = (E + nChunks - 1) / nChunks;
        int beg = chunk * per;
        int end = beg + per; if (end > E) end = E;
        for (int i = beg + (int)threadIdx.x; i < end; i += 256) {
            int dst = __builtin_nontemporal_load(&ei[E + i]);
            if (dst >= lo && dst < hi) {
                int src = __builtin_nontemporal_load(&ei[i]);
                int pos = atomicAdd(&cursor[dst], 1);
                srclist[pos] = src;
            }
        }
        return;
    }
    // ---- gemm1 path ----
    int gb = b - nScatter;
    int tid = threadIdx.x;
    for (int i = tid; i < 64 * 64; i += 256) Wl[i] = W[i];
    int r   = tid >> 6;
    int col = tid & 63;
    int row = gb * 4 + r;
    if (row < N) Xl[r][col] = x[(size_t)row * 64 + col];
    __syncthreads();
    if (row >= N) return;

    float acc = 0.f;
#pragma unroll
    for (int k = 0; k < 64; ++k) acc += Xl[r][k] * Wl[k * 64 + col];
    h1[(size_t)row * 64 + col] = acc;

    int head = col >> 5;
    float ps = acc * a_src[col];
    float pd = acc * a_dst[col];
#pragma unroll
    for (int off = 16; off; off >>= 1) {
        ps += __shfl_xor(ps, off, 32);
        pd += __shfl_xor(pd, off, 32);
    }
    if ((col & 31) == 0) {
        as1[row * 2 + head] = ps;
        ad1[row * 2 + head] = pd;
    }
}

// ---------------------------------------------------------------------------
// Layer-1 aggregation, gather-side: one 64-lane wave per dst node.
// ---------------------------------------------------------------------------
__global__ __launch_bounds__(256) void agg1_kernel(
    const int* __restrict__ rowptr, const int* __restrict__ srclist,
    const float* __restrict__ h1, const float* __restrict__ as1,
    const float* __restrict__ ad1, const float* __restrict__ b1,
    float* __restrict__ h1e, int N)
{
    int n = (blockIdx.x * 256 + threadIdx.x) >> 6;
    int lane = threadIdx.x & 63;
    if (n >= N) return;
    int head = lane >> 5;
    float adn = ad1[n * 2 + head];

    float w = __expf(lrelu_f(as1[n * 2 + head] + adn));
    float den = w;
    float acc = w * h1[(size_t)n * 64 + lane];

    int i = rowptr[n], endp = rowptr[n + 1];
    for (; i + 3 < endp; i += 4) {
        int s0 = srclist[i], s1 = srclist[i + 1];
        int s2 = srclist[i + 2], s3 = srclist[i + 3];
        float a0 = as1[s0 * 2 + head], a1 = as1[s1 * 2 + head];
        float a2 = as1[s2 * 2 + head], a3 = as1[s3 * 2 + head];
        float g0 = h1[(size_t)s0 * 64 + lane];
        float g1 = h1[(size_t)s1 * 64 + lane];
        float g2 = h1[(size_t)s2 * 64 + lane];
        float g3 = h1[(size_t)s3 * 64 + lane];
        float w0 = __expf(lrelu_f(a0 + adn));
        float w1 = __expf(lrelu_f(a1 + adn));
        float w2 = __expf(lrelu_f(a2 + adn));
        float w3 = __expf(lrelu_f(a3 + adn));
        den += (w0 + w1) + (w2 + w3);
        acc += w0 * g0 + w1 * g1 + w2 * g2 + w3 * g3;
    }
    for (; i < endp; ++i) {
        int s0 = srclist[i];
        float w0 = __expf(lrelu_f(as1[s0 * 2 + head] + adn));
        den += w0;
        acc += w0 * h1[(size_t)s0 * 64 + lane];
    }

    float v = acc / den + b1[lane];
    h1e[(size_t)n * 64 + lane] = elu_f(v);
}

// ---------------------------------------------------------------------------
// GEMM2: h2 = h1e @ W2 ([N,64] x [64,32]) with fused alpha2 reductions
// ---------------------------------------------------------------------------
__global__ __launch_bounds__(256) void gemm2_kernel(
    const float* __restrict__ xin, const float* __restrict__ W,
    const float* __restrict__ a_src, const float* __restrict__ a_dst,
    float* __restrict__ h2, float* __restrict__ as2, float* __restrict__ ad2,
    int N)
{
    __shared__ float Wl[64 * 32];
    __shared__ float Xl[8][64];
    int tid = threadIdx.x;
    for (int i = tid; i < 64 * 32; i += 256) Wl[i] = W[i];
    int base = blockIdx.x * 8;
    for (int i = tid; i < 8 * 64; i += 256) {
        int rr = i >> 6, cc = i & 63;
        if (base + rr < N) Xl[rr][cc] = xin[(size_t)(base + rr) * 64 + cc];
    }
    __syncthreads();
    int r   = tid >> 5;
    int col = tid & 31;
    int row = base + r;
    if (row >= N) return;

    float acc = 0.f;
#pragma unroll
    for (int k = 0; k < 64; ++k) acc += Xl[r][k] * Wl[k * 32 + col];
    h2[(size_t)row * 32 + col] = acc;

    float ps = acc * a_src[col];
    float pd = acc * a_dst[col];
#pragma unroll
    for (int off = 16; off; off >>= 1) {
        ps += __shfl_xor(ps, off, 32);
        pd += __shfl_xor(pd, off, 32);
    }
    if (col == 0) { as2[row] = ps; ad2[row] = pd; }
}

// ---------------------------------------------------------------------------
// Layer-2 aggregation, gather-side: 32 lanes per dst node, 4x unrolled.
// out layout: [0,N) scores, [N, N+N*32) h
// ---------------------------------------------------------------------------
__global__ __launch_bounds__(256) void agg2_kernel(
    const int* __restrict__ rowptr, const int* __restrict__ srclist,
    const float* __restrict__ h2, const float* __restrict__ as2,
    const float* __restrict__ ad2, const float* __restrict__ b2,
    const float* __restrict__ fcW, const float* __restrict__ fcb,
    float* __restrict__ out, int N)
{
    int g = blockIdx.x * 256 + threadIdx.x;
    int n = g >> 5;
    int lane = g & 31;
    if (n >= N) return;
    float adn = ad2[n];

    float w = __expf(lrelu_f(as2[n] + adn));
    float den = w;
    float acc = w * h2[(size_t)n * 32 + lane];

    int i = rowptr[n], endp = rowptr[n + 1];
    for (; i + 3 < endp; i += 4) {
        int s0 = srclist[i], s1 = srclist[i + 1];
        int s2 = srclist[i + 2], s3 = srclist[i + 3];
        float a0 = as2[s0], a1 = as2[s1], a2 = as2[s2], a3 = as2[s3];
        float g0 = h2[(size_t)s0 * 32 + lane];
        float g1 = h2[(size_t)s1 * 32 + lane];
        float g2 = h2[(size_t)s2 * 32 + lane];
        float g3 = h2[(size_t)s3 * 32 + lane];
        float w0 = __expf(lrelu_f(a0 + adn));
        float w1 = __expf(lrelu_f(a1 + adn));
        float w2 = __expf(lrelu_f(a2 + adn));
        float w3 = __expf(lrelu_f(a3 + adn));
        den += (w0 + w1) + (w2 + w3);
        acc += w0 * g0 + w1 * g1 + w2 * g2 + w3 * g3;
    }
    for (; i < endp; ++i) {
        int s0 = srclist[i];
        float w0 = __expf(lrelu_f(as2[s0] + adn));
        den += w0;
        acc += w0 * h2[(size_t)s0 * 32 + lane];
    }

    float v = elu_f(acc / den + b2[lane]);
    out[(size_t)N + (size_t)n * 32 + lane] = v;
    float p = v * fcW[lane];
#pragma unroll
    for (int off = 16; off; off >>= 1) p += __shfl_xor(p, off, 32);
    if (lane == 0) out[n] = p + fcb[0];
}

extern "C" void kernel_launch(void* const* d_in, const int* in_sizes, int n_in,
                              void* d_out, int out_size, void* d_ws, size_t ws_size,
                              hipStream_t stream) {
    const float* x    = (const float*)d_in[0];
    const int*   ei   = (const int*)d_in[1];
    const float* W1   = (const float*)d_in[2];
    const float* a_s1 = (const float*)d_in[3];
    const float* a_d1 = (const float*)d_in[4];
    const float* b1   = (const float*)d_in[5];
    const float* W2   = (const float*)d_in[6];
    const float* a_s2 = (const float*)d_in[7];
    const float* a_d2 = (const float*)d_in[8];
    const float* b2   = (const float*)d_in[9];
    const float* fcW  = (const float*)d_in[10];
    const float* fcb  = (const float*)d_in[11];

    const int N = in_sizes[0] / 64;
    const int E = in_sizes[1] / 2;

    float* fws  = (float*)d_ws;
    float* h1   = fws;                      // N*64  (reused as h2 after agg1)
    float* h1e  = h1   + (size_t)N * 64;    // N*64
    float* as1  = h1e  + (size_t)N * 64;    // N*2
    float* ad1  = as1  + (size_t)N * 2;     // N*2
    float* as2  = ad1  + (size_t)N * 2;     // N
    float* ad2  = as2  + (size_t)N;         // N
    int*   cnt     = (int*)(ad2 + (size_t)N);  // N   (histogram, then cursor)
    int*   rowptr  = cnt + N;                  // N+1
    int*   srclist = rowptr + N + 1;           // E
    int*   blocksum = srclist + E;             // ceil(N/SCAN_TILE)
    float* h2   = h1;                      // alias: h1 dead after agg1

    const int nScan = (N + SCAN_TILE - 1) / SCAN_TILE;

    hipMemsetAsync(cnt, 0, sizeof(int) * (size_t)N, stream);

    hist_kernel<<<(E + 255) / 256, 256, 0, stream>>>(ei, cnt, E);

    scan_partial_kernel<<<nScan, 256, 0, stream>>>(cnt, blocksum, N);
    scan_blocksum_kernel<<<1, 1024, 0, stream>>>(blocksum, nScan, rowptr, N, E);
    scan_final_kernel<<<nScan, 256, 0, stream>>>(cnt, blocksum, rowptr, N);

    const int nChunks = 256;  // 256 chunks x 8 ranges = 2048 scatter blocks
    const int nGemm1 = (N + 3) / 4;
    scatter_gemm1_kernel<<<nChunks * NRANGE + nGemm1, 256, 0, stream>>>(
        ei, cnt, srclist, E, N, nChunks, x, W1, a_s1, a_d1, h1, as1, ad1);

    agg1_kernel<<<((size_t)N * 64 + 255) / 256, 256, 0, stream>>>(
        rowptr, srclist, h1, as1, ad1, b1, h1e, N);

    gemm2_kernel<<<(N + 7) / 8, 256, 0, stream>>>(h1e, W2, a_s2, a_d2, h2, as2, ad2, N);

    agg2_kernel<<<((size_t)N * 32 + 255) / 256, 256, 0, stream>>>(
        rowptr, srclist, h2, as2, ad2, b2, fcW, fcb, (float*)d_out, N);
}

// Round 7
// 374.328 us; speedup vs baseline: 3.4502x; 1.0409x over previous
//
#include <hip/hip_runtime.h>
#include <hip/hip_fp16.h>

#define NEG_SLOPE 0.2f
#define NRANGE 8          // dst-range partitions == XCD count (b%8 heuristic)
#define SCAN_TILE 2048    // elements per scan block

__device__ __forceinline__ float elu_f(float x) {
    return x > 0.f ? x : __expf(x) - 1.f;
}
__device__ __forceinline__ float lrelu_f(float x) {
    return x > 0.f ? x : NEG_SLOPE * x;
}

// ---------------------------------------------------------------------------
// CSR build step 1: histogram of destination nodes (per-node counters:
// 50K counters, ~32 atomics each — low contention. Round-4 lesson: coarse
// bucket cursors serialize atomic-returns => 8x regression.)
// ---------------------------------------------------------------------------
__global__ __launch_bounds__(256) void hist_kernel(
    const int* __restrict__ ei, int* __restrict__ cnt, int E)
{
    int t = blockIdx.x * 256 + threadIdx.x;
    if (t < E) atomicAdd(&cnt[__builtin_nontemporal_load(&ei[E + t])], 1);
}

// ---------------------------------------------------------------------------
// Hierarchical scan phase A: per-tile sums.
// ---------------------------------------------------------------------------
__global__ __launch_bounds__(256) void scan_partial_kernel(
    const int* __restrict__ cnt, int* __restrict__ blocksum, int N)
{
    __shared__ int red[256];
    int base = blockIdx.x * SCAN_TILE;
    int s = 0;
#pragma unroll
    for (int k = 0; k < 8; ++k) {
        int i = base + k * 256 + threadIdx.x;
        if (i < N) s += cnt[i];
    }
    red[threadIdx.x] = s;
    __syncthreads();
    for (int off = 128; off; off >>= 1) {
        if (threadIdx.x < off) red[threadIdx.x] += red[threadIdx.x + off];
        __syncthreads();
    }
    if (threadIdx.x == 0) blocksum[blockIdx.x] = red[0];
}

// ---------------------------------------------------------------------------
// Hierarchical scan phase B: exclusive scan of tile sums; rowptr[N]=E.
// ---------------------------------------------------------------------------
__global__ __launch_bounds__(1024) void scan_blocksum_kernel(
    int* __restrict__ blocksum, int nb, int* __restrict__ rowptr, int N, int E)
{
    __shared__ int part[1024];
    int t = threadIdx.x;
    part[t] = (t < nb) ? blocksum[t] : 0;
    __syncthreads();
    for (int off = 1; off < 1024; off <<= 1) {
        int v = (t >= off) ? part[t - off] : 0;
        __syncthreads();
        part[t] += v;
        __syncthreads();
    }
    if (t < nb) blocksum[t] = (t == 0) ? 0 : part[t - 1];  // exclusive
    if (t == 0) rowptr[N] = E;
}

// ---------------------------------------------------------------------------
// Hierarchical scan phase C: tile-local exclusive scan + tile offset;
// writes rowptr and scatter cursor (cursor aliases cnt).
// ---------------------------------------------------------------------------
__global__ __launch_bounds__(256) void scan_final_kernel(
    int* __restrict__ cnt, const int* __restrict__ blocksum,
    int* __restrict__ rowptr, int N)
{
    __shared__ int lds[SCAN_TILE];
    __shared__ int tsum[256];
    int base = blockIdx.x * SCAN_TILE;
    int tid = threadIdx.x;
#pragma unroll
    for (int k = 0; k < 8; ++k) {
        int i = base + k * 256 + tid;
        lds[k * 256 + tid] = (i < N) ? cnt[i] : 0;
    }
    __syncthreads();
    int my[8];
    int s = 0;
#pragma unroll
    for (int j = 0; j < 8; ++j) { my[j] = s; s += lds[tid * 8 + j]; }
    tsum[tid] = s;
    __syncthreads();
    for (int off = 1; off < 256; off <<= 1) {
        int v = (tid >= off) ? tsum[tid - off] : 0;
        __syncthreads();
        tsum[tid] += v;
        __syncthreads();
    }
    int texcl = (tid == 0) ? 0 : tsum[tid - 1];
    int boff = blocksum[blockIdx.x];
    __syncthreads();
#pragma unroll
    for (int j = 0; j < 8; ++j) lds[tid * 8 + j] = boff + texcl + my[j];
    __syncthreads();
#pragma unroll
    for (int k = 0; k < 8; ++k) {
        int i = base + k * 256 + tid;
        if (i < N) {
            int v = lds[k * 256 + tid];
            rowptr[i] = v;
            cnt[i] = v;      // scatter cursor
        }
    }
}

// ---------------------------------------------------------------------------
// Fused: CSR scatter (blocks [0, nChunks*NRANGE)) + GEMM1 (remaining blocks).
// srclist is ushort (N<65536): halves payload AND halves partial-line
// writeback inflation. GEMM1 writes h1 in fp16 (halves agg1 gather bytes);
// alpha reductions stay fp32 from the exact fp32 accumulator.
// ---------------------------------------------------------------------------
__global__ __launch_bounds__(256) void scatter_gemm1_kernel(
    const int* __restrict__ ei, int* __restrict__ cursor,
    unsigned short* __restrict__ srclist, int E, int N, int nChunks,
    const float* __restrict__ x, const float* __restrict__ W,
    const float* __restrict__ a_src, const float* __restrict__ a_dst,
    __half* __restrict__ h1, float* __restrict__ as1, float* __restrict__ ad1)
{
    __shared__ float Wl[64 * 64];
    __shared__ float Xl[4][64];
    int b = blockIdx.x;
    int nScatter = nChunks * NRANGE;
    if (b < nScatter) {
        // ---- scatter path (XCD-range-affine via b%8, per-node cursors) ----
        int range = b & (NRANGE - 1);
        int chunk = b >> 3;
        int RS = (N + NRANGE - 1) / NRANGE;
        int lo = range * RS;
        int hi = lo + RS; if (hi > N) hi = N;
        int per = (E + nChunks - 1) / nChunks;
        int beg = chunk * per;
        int end = beg + per; if (end > E) end = E;
        for (int i = beg + (int)threadIdx.x; i < end; i += 256) {
            int dst = __builtin_nontemporal_load(&ei[E + i]);
            if (dst >= lo && dst < hi) {
                int src = __builtin_nontemporal_load(&ei[i]);
                int pos = atomicAdd(&cursor[dst], 1);
                srclist[pos] = (unsigned short)src;
            }
        }
        return;
    }
    // ---- gemm1 path ----
    int gb = b - nScatter;
    int tid = threadIdx.x;
    for (int i = tid; i < 64 * 64; i += 256) Wl[i] = W[i];
    int r   = tid >> 6;
    int col = tid & 63;
    int row = gb * 4 + r;
    if (row < N) Xl[r][col] = x[(size_t)row * 64 + col];
    __syncthreads();
    if (row >= N) return;

    float acc = 0.f;
#pragma unroll
    for (int k = 0; k < 64; ++k) acc += Xl[r][k] * Wl[k * 64 + col];
    h1[(size_t)row * 64 + col] = __float2half(acc);

    int head = col >> 5;
    float ps = acc * a_src[col];
    float pd = acc * a_dst[col];
#pragma unroll
    for (int off = 16; off; off >>= 1) {
        ps += __shfl_xor(ps, off, 32);
        pd += __shfl_xor(pd, off, 32);
    }
    if ((col & 31) == 0) {
        as1[row * 2 + head] = ps;
        ad1[row * 2 + head] = pd;
    }
}

// ---------------------------------------------------------------------------
// Fused layer-1 aggregation + GEMM2 + alpha2. One 64-lane wave per dst node:
// aggregate (fp16 h1 gathers), h1e row stays in registers -> per-wave LDS row,
// 64x32 GEMM2 via half-wave k-split + shfl_xor(32) combine, write h2 (fp32),
// as2/ad2. Eliminates the h1e global round-trip and the gemm2 launch.
// ---------------------------------------------------------------------------
__global__ __launch_bounds__(256) void agg1_gemm2_kernel(
    const int* __restrict__ rowptr, const unsigned short* __restrict__ srclist,
    const __half* __restrict__ h1, const float* __restrict__ as1,
    const float* __restrict__ ad1, const float* __restrict__ b1,
    const float* __restrict__ W2, const float* __restrict__ a_s2,
    const float* __restrict__ a_d2,
    float* __restrict__ h2, float* __restrict__ as2, float* __restrict__ ad2,
    int N)
{
    __shared__ float W2l[64 * 32];
    __shared__ float sh[4][64];
    int tid = threadIdx.x;
    for (int i = tid; i < 64 * 32; i += 256) W2l[i] = W2[i];
    __syncthreads();   // block-uniform: all threads reach this

    int n = (blockIdx.x * 256 + tid) >> 6;
    int lane = tid & 63;
    int wid = tid >> 6;
    if (n >= N) return;

    int head = lane >> 5;
    float adn = ad1[n * 2 + head];

    // self-loop
    float w = __expf(lrelu_f(as1[n * 2 + head] + adn));
    float den = w;
    float acc = w * __half2float(h1[(size_t)n * 64 + lane]);

    int i = rowptr[n], endp = rowptr[n + 1];
    for (; i + 3 < endp; i += 4) {
        int s0 = srclist[i], s1 = srclist[i + 1];
        int s2 = srclist[i + 2], s3 = srclist[i + 3];
        float a0 = as1[s0 * 2 + head], a1 = as1[s1 * 2 + head];
        float a2 = as1[s2 * 2 + head], a3 = as1[s3 * 2 + head];
        float g0 = __half2float(h1[(size_t)s0 * 64 + lane]);
        float g1 = __half2float(h1[(size_t)s1 * 64 + lane]);
        float g2 = __half2float(h1[(size_t)s2 * 64 + lane]);
        float g3 = __half2float(h1[(size_t)s3 * 64 + lane]);
        float w0 = __expf(lrelu_f(a0 + adn));
        float w1 = __expf(lrelu_f(a1 + adn));
        float w2 = __expf(lrelu_f(a2 + adn));
        float w3 = __expf(lrelu_f(a3 + adn));
        den += (w0 + w1) + (w2 + w3);
        acc += w0 * g0 + w1 * g1 + w2 * g2 + w3 * g3;
    }
    for (; i < endp; ++i) {
        int s0 = srclist[i];
        float w0 = __expf(lrelu_f(as1[s0 * 2 + head] + adn));
        den += w0;
        acc += w0 * __half2float(h1[(size_t)s0 * 64 + lane]);
    }

    float v = elu_f(acc / den + b1[lane]);   // h1e[n, lane]

    // ---- fused GEMM2: h2[n, col] = sum_k h1e[n,k] * W2[k, col] ----
    sh[wid][lane] = v;          // per-wave row; within-wave LDS ordering
    int col = lane & 31;
    int kbase = (lane >> 5) * 32;   // lanes 0-31: k 0..31, lanes 32-63: k 32..63
    float p = 0.f;
#pragma unroll
    for (int j = 0; j < 32; ++j)
        p += sh[wid][kbase + j] * W2l[(kbase + j) * 32 + col];
    p += __shfl_xor(p, 32, 64);     // combine the two k-halves; all lanes valid

    if (lane < 32) h2[(size_t)n * 32 + lane] = p;

    float ps = p * a_s2[col];
    float pd = p * a_d2[col];
#pragma unroll
    for (int off = 16; off; off >>= 1) {
        ps += __shfl_xor(ps, off, 32);
        pd += __shfl_xor(pd, off, 32);
    }
    if (lane == 0) { as2[n] = ps; ad2[n] = pd; }
}

// ---------------------------------------------------------------------------
// Layer-2 aggregation, gather-side: 32 lanes per dst node, 4x unrolled.
// out layout: [0,N) scores, [N, N+N*32) h
// ---------------------------------------------------------------------------
__global__ __launch_bounds__(256) void agg2_kernel(
    const int* __restrict__ rowptr, const unsigned short* __restrict__ srclist,
    const float* __restrict__ h2, const float* __restrict__ as2,
    const float* __restrict__ ad2, const float* __restrict__ b2,
    const float* __restrict__ fcW, const float* __restrict__ fcb,
    float* __restrict__ out, int N)
{
    int g = blockIdx.x * 256 + threadIdx.x;
    int n = g >> 5;
    int lane = g & 31;
    if (n >= N) return;
    float adn = ad2[n];

    float w = __expf(lrelu_f(as2[n] + adn));
    float den = w;
    float acc = w * h2[(size_t)n * 32 + lane];

    int i = rowptr[n], endp = rowptr[n + 1];
    for (; i + 3 < endp; i += 4) {
        int s0 = srclist[i], s1 = srclist[i + 1];
        int s2 = srclist[i + 2], s3 = srclist[i + 3];
        float a0 = as2[s0], a1 = as2[s1], a2 = as2[s2], a3 = as2[s3];
        float g0 = h2[(size_t)s0 * 32 + lane];
        float g1 = h2[(size_t)s1 * 32 + lane];
        float g2 = h2[(size_t)s2 * 32 + lane];
        float g3 = h2[(size_t)s3 * 32 + lane];
        float w0 = __expf(lrelu_f(a0 + adn));
        float w1 = __expf(lrelu_f(a1 + adn));
        float w2 = __expf(lrelu_f(a2 + adn));
        float w3 = __expf(lrelu_f(a3 + adn));
        den += (w0 + w1) + (w2 + w3);
        acc += w0 * g0 + w1 * g1 + w2 * g2 + w3 * g3;
    }
    for (; i < endp; ++i) {
        int s0 = srclist[i];
        float w0 = __expf(lrelu_f(as2[s0] + adn));
        den += w0;
        acc += w0 * h2[(size_t)s0 * 32 + lane];
    }

    float v = elu_f(acc / den + b2[lane]);
    out[(size_t)N + (size_t)n * 32 + lane] = v;
    float p = v * fcW[lane];
#pragma unroll
    for (int off = 16; off; off >>= 1) p += __shfl_xor(p, off, 32);
    if (lane == 0) out[n] = p + fcb[0];
}

extern "C" void kernel_launch(void* const* d_in, const int* in_sizes, int n_in,
                              void* d_out, int out_size, void* d_ws, size_t ws_size,
                              hipStream_t stream) {
    const float* x    = (const float*)d_in[0];
    const int*   ei   = (const int*)d_in[1];
    const float* W1   = (const float*)d_in[2];
    const float* a_s1 = (const float*)d_in[3];
    const float* a_d1 = (const float*)d_in[4];
    const float* b1   = (const float*)d_in[5];
    const float* W2   = (const float*)d_in[6];
    const float* a_s2 = (const float*)d_in[7];
    const float* a_d2 = (const float*)d_in[8];
    const float* b2   = (const float*)d_in[9];
    const float* fcW  = (const float*)d_in[10];
    const float* fcb  = (const float*)d_in[11];

    const int N = in_sizes[0] / 64;
    const int E = in_sizes[1] / 2;
    const int nScan = (N + SCAN_TILE - 1) / SCAN_TILE;

    // Workspace layout: fp32 arrays, then fp16 h1, then ints, then ushort.
    float* fws  = (float*)d_ws;
    float* as1  = fws;                      // 2N
    float* ad1  = as1 + (size_t)2 * N;      // 2N
    float* as2  = ad1 + (size_t)2 * N;      // N
    float* ad2  = as2 + (size_t)N;          // N
    float* h2   = ad2 + (size_t)N;          // 32N
    __half* h1  = (__half*)(h2 + (size_t)32 * N);   // 64N halves (=32N floats)
    int*   cnt     = (int*)(h1 + (size_t)64 * N);   // N (histogram -> cursor)
    int*   rowptr  = cnt + N;                       // N+1
    int*   blocksum = rowptr + N + 1;               // nScan
    unsigned short* srclist = (unsigned short*)(blocksum + nScan);  // E

    hipMemsetAsync(cnt, 0, sizeof(int) * (size_t)N, stream);

    hist_kernel<<<(E + 255) / 256, 256, 0, stream>>>(ei, cnt, E);

    scan_partial_kernel<<<nScan, 256, 0, stream>>>(cnt, blocksum, N);
    scan_blocksum_kernel<<<1, 1024, 0, stream>>>(blocksum, nScan, rowptr, N, E);
    scan_final_kernel<<<nScan, 256, 0, stream>>>(cnt, blocksum, rowptr, N);

    const int nChunks = 256;  // 256 chunks x 8 ranges = 2048 scatter blocks
    const int nGemm1 = (N + 3) / 4;
    scatter_gemm1_kernel<<<nChunks * NRANGE + nGemm1, 256, 0, stream>>>(
        ei, cnt, srclist, E, N, nChunks, x, W1, a_s1, a_d1, h1, as1, ad1);

    agg1_gemm2_kernel<<<((size_t)N * 64 + 255) / 256, 256, 0, stream>>>(
        rowptr, srclist, h1, as1, ad1, b1, W2, a_s2, a_d2, h2, as2, ad2, N);

    agg2_kernel<<<((size_t)N * 32 + 255) / 256, 256, 0, stream>>>(
        rowptr, srclist, h2, as2, ad2, b2, fcW, fcb, (float*)d_out, N);
}